// Round 5
// baseline (132.256 us; speedup 1.0000x reference)
//
#include <hip/hip_runtime.h>

#define NJ 8
#define TS 2048
#define NB 1024
#define CHUNK 256              // 64 lanes * 4 steps per wave-scan
#define NCH (TS / CHUNK)       // 8
#define F4C (CHUNK * NJ)       // 2048 float4 = 32 KB
#define DTC (1.0f / 60.0f)

__global__ __launch_bounds__(512, 8) void phys_scan4_kernel(
    const float4* __restrict__ x,       // (B,T,8) as float4 per (t,joint)
    const float*  __restrict__ state0,  // (B,8,2)
    const float*  __restrict__ M,       // (8,2)
    const float*  __restrict__ inertia, // (8,)
    const float*  __restrict__ damping, // (8,)
    float* __restrict__ out,            // (B,T,8)
    float* __restrict__ muscle,         // (B,8,2,2)
    float* __restrict__ finals)         // (B,8,2)
{
    __shared__ float4 xin[F4C];        // 32 KB input chunk
    __shared__ float4 tout4[CHUNK * NJ / 4]; // 8 KB theta transpose buffer
    float* tout = (float*)tout4;

    const int b    = blockIdx.x;
    const int tid  = threadIdx.x;
    const int j    = tid >> 6;          // wave id = joint index
    const int lane = tid & 63;

    const float M0  = M[j * 2 + 0];
    const float M1  = M[j * 2 + 1];
    const float M20 = M0 * M0;
    const float M21 = M1 * M1;
    const float d   = damping[j];
    const float p   = DTC / inertia[j];      // DT / I
    const float g   = 1.0f - p * d;          // dθ self-coefficient

    float thc  = state0[(b * NJ + j) * 2 + 0];
    float dthc = state0[(b * NJ + j) * 2 + 1];

    const float4* xb = x + (size_t)b * TS * NJ;

    // prologue: prefetch chunk 0 and stage it (4 float4 per thread)
    float4 stage[4];
    #pragma unroll
    for (int i = 0; i < 4; ++i) stage[i] = xb[512 * i + tid];
    #pragma unroll
    for (int i = 0; i < 4; ++i) {
        int idx = 512 * i + tid;
        xin[idx ^ ((idx >> 6) & 7)] = stage[i];
    }

    for (int ch = 0; ch < NCH; ++ch) {
        __syncthreads();   // S1: staging visible; prev θ-reads complete

        // prefetch next chunk into regs (drains while we compute this chunk)
        if (ch + 1 < NCH) {
            #pragma unroll
            for (int i = 0; i < 4; ++i)
                stage[i] = xb[(size_t)(ch + 1) * F4C + 512 * i + tid];
        }

        // read my 4 consecutive steps; element (step s=4*lane+k, joint j)
        // natural idx = 32*lane + 8k + j, swizzle ^((idx>>6)&7) = ^((lane>>1)&7)
        float a[4], c[4];
        const int base = 32 * lane + (j ^ ((lane >> 1) & 7));
        #pragma unroll
        for (int k = 0; k < 4; ++k) {
            float4 v = xin[base + 8 * k];
            a[k] = fmaf(M0,  v.x, M1  * v.y);   // einsum(M, F_t)
            c[k] = fmaf(M20, v.z, M21 * v.w);   // einsum(M2, K_t)
        }

        // serially compose my 4 step-maps:
        //   dθ' = r0·θ + r1·dθ + rc ;  θ' = s0·θ + s1·dθ + sc
        float r0 = 0.0f, r1 = 1.0f, rc = 0.0f;   // identity
        float s0 = 1.0f, s1 = 0.0f, sc = 0.0f;
        #pragma unroll
        for (int k = 0; k < 4; ++k) {
            float pa = p * a[k];
            float pc = p * c[k];
            float nr0 = fmaf(-pc, s0, g * r0);
            float nr1 = fmaf(-pc, s1, g * r1);
            float nrc = fmaf(-pc, sc, fmaf(g, rc, pa));
            s0 = fmaf(DTC, nr0, s0);
            s1 = fmaf(DTC, nr1, s1);
            sc = fmaf(DTC, nrc, sc);
            r0 = nr0; r1 = nr1; rc = nrc;
        }

        // inclusive Kogge-Stone over 64 lanes (compose: mine ∘ other)
        #pragma unroll
        for (int delta = 1; delta < 64; delta <<= 1) {
            float o_r0 = __shfl_up(r0, delta, 64);
            float o_r1 = __shfl_up(r1, delta, 64);
            float o_rc = __shfl_up(rc, delta, 64);
            float o_s0 = __shfl_up(s0, delta, 64);
            float o_s1 = __shfl_up(s1, delta, 64);
            float o_sc = __shfl_up(sc, delta, 64);
            if (lane >= delta) {
                float nr0 = fmaf(r0, o_s0, r1 * o_r0);
                float nr1 = fmaf(r0, o_s1, r1 * o_r1);
                float nrc = fmaf(r0, o_sc, fmaf(r1, o_rc, rc));
                float ns0 = fmaf(s0, o_s0, s1 * o_r0);
                float ns1 = fmaf(s0, o_s1, s1 * o_r1);
                float nsc = fmaf(s0, o_sc, fmaf(s1, o_rc, sc));
                r0 = nr0; r1 = nr1; rc = nrc;
                s0 = ns0; s1 = ns1; sc = nsc;
            }
        }

        // exclusive prefix: lane l uses inclusive result of lane l-1
        float e_r0 = __shfl_up(r0, 1, 64);
        float e_r1 = __shfl_up(r1, 1, 64);
        float e_rc = __shfl_up(rc, 1, 64);
        float e_s0 = __shfl_up(s0, 1, 64);
        float e_s1 = __shfl_up(s1, 1, 64);
        float e_sc = __shfl_up(sc, 1, 64);
        if (lane == 0) {
            e_r0 = 0.0f; e_r1 = 1.0f; e_rc = 0.0f;
            e_s0 = 1.0f; e_s1 = 0.0f; e_sc = 0.0f;
        }

        // state at my first step
        float th  = fmaf(e_s0, thc, fmaf(e_s1, dthc, e_sc));
        float dth = fmaf(e_r0, thc, fmaf(e_r1, dthc, e_rc));

        // replay 4 steps in exact reference op-order; θ -> LDS transpose buf.
        // word w = 32*lane + 8k + j; swizzle w' = w ^ ((w>>6)&31) = w ^ ((lane>>1)&31)
        const int wsig = (lane >> 1) & 31;
        #pragma unroll
        for (int k = 0; k < 4; ++k) {
            float u = fmaf(-c[k], th, a[k]);     // a - c·θ
            u = fmaf(-d, dth, u);                // ... - d·dθ
            dth = fmaf(p, u, dth);
            th  = fmaf(DTC, dth, th);
            tout[(32 * lane + 8 * k + j) ^ wsig] = th;
        }

        // carry = lane 63's end state
        thc  = __shfl(th, 63, 64);
        dthc = __shfl(dth, 63, 64);

        __syncthreads();   // S2: θ visible; all a,c reads complete

        // stage next chunk into input LDS (safe: a,c reads done at S2)
        if (ch + 1 < NCH) {
            #pragma unroll
            for (int i = 0; i < 4; ++i) {
                int idx = 512 * i + tid;
                xin[idx ^ ((idx >> 6) & 7)] = stage[i];
            }
        }

        // coalesced output: thread tid handles out-float4 f = tid.
        // out word w = 4f+i stored at w ^ m, m = (w>>6)&31 = (f>>4)&31.
        // aligned b128 at float4 idx f ^ (m>>2); components permuted by m&3.
        float* outc = out + ((size_t)b * TS + (size_t)ch * CHUNK) * NJ;
        {
            int f  = tid;
            int m  = (f >> 4) & 31;
            int pm = m & 3;
            float4 r = tout4[f ^ (m >> 2)];
            float rx = r.x, ry = r.y, rz = r.z, rw = r.w;
            if (pm & 1) { float tq = rx; rx = ry; ry = tq; tq = rz; rz = rw; rw = tq; }
            if (pm & 2) { float tq = rx; rx = rz; rz = tq; tq = ry; ry = rw; rw = tq; }
            ((float4*)outc)[f] = make_float4(rx, ry, rz, rw);
        }
    }

    if (lane == 0) {
        const int idx = b * NJ + j;
        finals[idx * 2 + 0] = thc;
        finals[idx * 2 + 1] = dthc;
        muscle[idx * 4 + 0] = thc  * M0;
        muscle[idx * 4 + 1] = thc  * M1;
        muscle[idx * 4 + 2] = dthc * M0;
        muscle[idx * 4 + 3] = dthc * M1;
    }
}

extern "C" void kernel_launch(void* const* d_in, const int* in_sizes, int n_in,
                              void* d_out, int out_size, void* d_ws, size_t ws_size,
                              hipStream_t stream) {
    const float4* x      = (const float4*)d_in[0];
    const float*  state0 = (const float*)d_in[1];
    const float*  M      = (const float*)d_in[2];
    const float*  inertia= (const float*)d_in[3];
    const float*  damping= (const float*)d_in[4];

    float* out    = (float*)d_out;                       // (B,T,8)
    float* muscle = out + (size_t)NB * TS * NJ;          // (B,8,2,2)
    float* finals = muscle + (size_t)NB * NJ * 2 * 2;    // (B,8,2)

    dim3 block(512);          // 8 waves = 8 joints of one batch
    dim3 grid(NB);
    phys_scan4_kernel<<<grid, block, 0, stream>>>(x, state0, M, inertia, damping,
                                                  out, muscle, finals);
}

// Round 6
// 75.042 us; speedup vs baseline: 1.7624x; 1.7624x over previous
//
#include <hip/hip_runtime.h>

#define NJ 8
#define TS 2048
#define NB 1024
#define CHUNK 256               // 64 lanes * 4 steps per wave-scan
#define NCH (TS / CHUNK)        // 8
#define F4C (CHUNK * NJ)        // 2048 float4 = 32 KB per buffer
#define DTC (1.0f / 60.0f)

// async global->LDS, 16B per lane. lds_base must be wave-uniform; HW writes
// lds_base + lane*16. Global src is per-lane.
__device__ __forceinline__ void dma16(const float4* g, float4* lds_base) {
#if __has_builtin(__builtin_amdgcn_global_load_lds)
    __builtin_amdgcn_global_load_lds(
        (const __attribute__((address_space(1))) void*)g,
        (__attribute__((address_space(3))) void*)lds_base,
        16, 0, 0);
#else
    lds_base[threadIdx.x & 63] = *g;
#endif
}

__global__ __launch_bounds__(512, 4) void phys_pipe_kernel(
    const float4* __restrict__ x,       // (B,T,8) as float4 per (t,joint)
    const float*  __restrict__ state0,  // (B,8,2)
    const float*  __restrict__ M,       // (8,2)
    const float*  __restrict__ inertia, // (8,)
    const float*  __restrict__ damping, // (8,)
    float* __restrict__ out,            // (B,T,8)
    float* __restrict__ muscle,         // (B,8,2,2)
    float* __restrict__ finals)         // (B,8,2)
{
    __shared__ float4 xin[2][F4C];           // 2 x 32 KB input double-buffer
    __shared__ float4 tb[2][CHUNK * NJ / 4]; // 2 x 8 KB theta transpose dbuf

    const int b    = blockIdx.x;
    const int tid  = threadIdx.x;
    const int j    = tid >> 6;          // wave id = joint index
    const int lane = tid & 63;

    const float M0  = M[j * 2 + 0];
    const float M1  = M[j * 2 + 1];
    const float M20 = M0 * M0;
    const float M21 = M1 * M1;
    const float d   = damping[j];
    const float p   = DTC / inertia[j];      // DT / I
    const float g   = 1.0f - p * d;          // dθ self-coefficient

    float thc  = state0[(b * NJ + j) * 2 + 0];
    float dthc = state0[(b * NJ + j) * 2 + 1];

    const float4* xb = x + (size_t)b * TS * NJ;
    const int wv = j;   // wave index == joint

    // prologue: async-stage chunk 0.
    // dest idx (linear) = 512i + 64w + lane; src idx = dest ^ ((dest>>6)&7)
    //                   = 512i + 64w + (lane^w)   (pre-swizzled global source)
    {
        float4* lb = &xin[0][64 * wv];
        const float4* gb = xb + 64 * wv + (lane ^ wv);
        #pragma unroll
        for (int i = 0; i < 4; ++i) dma16(gb + 512 * i, lb + 512 * i);
    }

    for (int ch = 0; ch <= NCH; ++ch) {
        // single barrier per chunk: drains DMA(ch) [vmcnt] and makes
        // tout(ch-1) visible [lgkmcnt]; also buffer-overwrite safety.
        __syncthreads();

        // issue DMA for chunk ch+1 into the other xin buffer (full-chunk slack)
        if (ch + 1 < NCH) {
            float4* lb = &xin[(ch + 1) & 1][64 * wv];
            const float4* gb = xb + (size_t)(ch + 1) * F4C + 64 * wv + (lane ^ wv);
            #pragma unroll
            for (int i = 0; i < 4; ++i) dma16(gb + 512 * i, lb + 512 * i);
        }

        // ---- store phase: coalesced write-out of chunk ch-1's theta ----
        if (ch > 0) {
            const float4* tr = tb[(ch - 1) & 1];
            float* outc = out + ((size_t)b * TS + (size_t)(ch - 1) * CHUNK) * NJ;
            int f  = tid;
            int m  = (f >> 4) & 31;
            int pm = m & 3;
            float4 r = tr[f ^ (m >> 2)];
            float rx = r.x, ry = r.y, rz = r.z, rw = r.w;
            if (pm & 1) { float tq = rx; rx = ry; ry = tq; tq = rz; rz = rw; rw = tq; }
            if (pm & 2) { float tq = rx; rx = rz; rz = tq; tq = ry; ry = rw; rw = tq; }
            ((float4*)outc)[f] = make_float4(rx, ry, rz, rw);
        }

        if (ch < NCH) {
            // ---- compute phase on xin[ch&1] ----
            const float4* xc = xin[ch & 1];
            float* tw = (float*)tb[ch & 1];

            // element (step s=4*lane+k, joint j): natural idx 32*lane+8k+j,
            // swizzle ^((idx>>6)&7) = ^((lane>>1)&7)
            float a[4], c[4];
            const int base = 32 * lane + (j ^ ((lane >> 1) & 7));
            #pragma unroll
            for (int k = 0; k < 4; ++k) {
                float4 v = xc[base + 8 * k];
                a[k] = fmaf(M0,  v.x, M1  * v.y);   // einsum(M, F_t)
                c[k] = fmaf(M20, v.z, M21 * v.w);   // einsum(M2, K_t)
            }

            // serially compose my 4 step-maps:
            //   dθ' = r0·θ + r1·dθ + rc ;  θ' = s0·θ + s1·dθ + sc
            float r0 = 0.0f, r1 = 1.0f, rc = 0.0f;   // identity
            float s0 = 1.0f, s1 = 0.0f, sc = 0.0f;
            #pragma unroll
            for (int k = 0; k < 4; ++k) {
                float pa = p * a[k];
                float pc = p * c[k];
                float nr0 = fmaf(-pc, s0, g * r0);
                float nr1 = fmaf(-pc, s1, g * r1);
                float nrc = fmaf(-pc, sc, fmaf(g, rc, pa));
                s0 = fmaf(DTC, nr0, s0);
                s1 = fmaf(DTC, nr1, s1);
                sc = fmaf(DTC, nrc, sc);
                r0 = nr0; r1 = nr1; rc = nrc;
            }

            // inclusive Kogge-Stone over 64 lanes (compose: mine ∘ other)
            #pragma unroll
            for (int delta = 1; delta < 64; delta <<= 1) {
                float o_r0 = __shfl_up(r0, delta, 64);
                float o_r1 = __shfl_up(r1, delta, 64);
                float o_rc = __shfl_up(rc, delta, 64);
                float o_s0 = __shfl_up(s0, delta, 64);
                float o_s1 = __shfl_up(s1, delta, 64);
                float o_sc = __shfl_up(sc, delta, 64);
                if (lane >= delta) {
                    float nr0 = fmaf(r0, o_s0, r1 * o_r0);
                    float nr1 = fmaf(r0, o_s1, r1 * o_r1);
                    float nrc = fmaf(r0, o_sc, fmaf(r1, o_rc, rc));
                    float ns0 = fmaf(s0, o_s0, s1 * o_r0);
                    float ns1 = fmaf(s0, o_s1, s1 * o_r1);
                    float nsc = fmaf(s0, o_sc, fmaf(s1, o_rc, sc));
                    r0 = nr0; r1 = nr1; rc = nrc;
                    s0 = ns0; s1 = ns1; sc = nsc;
                }
            }

            // exclusive prefix: lane l uses inclusive result of lane l-1
            float e_r0 = __shfl_up(r0, 1, 64);
            float e_r1 = __shfl_up(r1, 1, 64);
            float e_rc = __shfl_up(rc, 1, 64);
            float e_s0 = __shfl_up(s0, 1, 64);
            float e_s1 = __shfl_up(s1, 1, 64);
            float e_sc = __shfl_up(sc, 1, 64);
            if (lane == 0) {
                e_r0 = 0.0f; e_r1 = 1.0f; e_rc = 0.0f;
                e_s0 = 1.0f; e_s1 = 0.0f; e_sc = 0.0f;
            }

            // state at my first step
            float th  = fmaf(e_s0, thc, fmaf(e_s1, dthc, e_sc));
            float dth = fmaf(e_r0, thc, fmaf(e_r1, dthc, e_rc));

            // replay 4 steps in exact reference op-order; θ -> transpose buf.
            // word w = 32*lane+8k+j; swizzle ^((w>>6)&31) = ^((lane>>1)&31)
            const int wsig = (lane >> 1) & 31;
            #pragma unroll
            for (int k = 0; k < 4; ++k) {
                float u = fmaf(-c[k], th, a[k]);     // a - c·θ
                u = fmaf(-d, dth, u);                // ... - d·dθ
                dth = fmaf(p, u, dth);
                th  = fmaf(DTC, dth, th);
                tw[(32 * lane + 8 * k + j) ^ wsig] = th;
            }

            // carry = lane 63's end state (uniform lane -> v_readlane, free)
            thc  = __shfl(th, 63, 64);
            dthc = __shfl(dth, 63, 64);
        }
    }

    if (lane == 0) {
        const int idx = b * NJ + j;
        finals[idx * 2 + 0] = thc;
        finals[idx * 2 + 1] = dthc;
        muscle[idx * 4 + 0] = thc  * M0;
        muscle[idx * 4 + 1] = thc  * M1;
        muscle[idx * 4 + 2] = dthc * M0;
        muscle[idx * 4 + 3] = dthc * M1;
    }
}

extern "C" void kernel_launch(void* const* d_in, const int* in_sizes, int n_in,
                              void* d_out, int out_size, void* d_ws, size_t ws_size,
                              hipStream_t stream) {
    const float4* x      = (const float4*)d_in[0];
    const float*  state0 = (const float*)d_in[1];
    const float*  M      = (const float*)d_in[2];
    const float*  inertia= (const float*)d_in[3];
    const float*  damping= (const float*)d_in[4];

    float* out    = (float*)d_out;                       // (B,T,8)
    float* muscle = out + (size_t)NB * TS * NJ;          // (B,8,2,2)
    float* finals = muscle + (size_t)NB * NJ * 2 * 2;    // (B,8,2)

    dim3 block(512);          // 8 waves = 8 joints of one batch
    dim3 grid(NB);
    phys_pipe_kernel<<<grid, block, 0, stream>>>(x, state0, M, inertia, damping,
                                                 out, muscle, finals);
}